// Round 1
// baseline (543.927 us; speedup 1.0000x reference)
//
#include <hip/hip_runtime.h>

// SpecCnn1d: y[b,o,f] = relu( sum_k x[b, o+k] * w[f,k] ), stride 1
// B=64, L=16384, F=128, K=16, out_len = L-K+1 = 16369
// Output 536 MB fp32 -> HBM write-bound, roofline ~85-95 us.

constexpr int K_TAPS  = 16;
constexpr int F_FILT  = 128;
constexpr int O_TILE  = 64;   // o positions per block
constexpr int O_CHUNK = 8;    // o positions per inner step

__global__ __launch_bounds__(F_FILT) void SpecCnn1d_conv_kernel(
    const float* __restrict__ x,     // [B, L]
    const float* __restrict__ w,     // [F, K]
    float* __restrict__ y,           // [B, out_len, F]
    int L, int out_len)
{
    const int f  = threadIdx.x;          // 0..127 -> filter index (lane dim)
    const int b  = blockIdx.y;
    const int o0 = blockIdx.x * O_TILE;

    // Filter taps -> registers. Lane f reads 64 contiguous bytes at offset
    // f*64: wave covers 4 KB contiguous, fully coalesced.
    float wr[K_TAPS];
    const float4* w4 = reinterpret_cast<const float4*>(w + f * K_TAPS);
    #pragma unroll
    for (int i = 0; i < K_TAPS / 4; ++i) {
        float4 v = w4[i];
        wr[4 * i + 0] = v.x;
        wr[4 * i + 1] = v.y;
        wr[4 * i + 2] = v.z;
        wr[4 * i + 3] = v.w;
    }

    const float* xb = x + (size_t)b * L;
    float*       yb = y + ((size_t)b * out_len + o0) * F_FILT + f;

    for (int oc = 0; oc < O_TILE; oc += O_CHUNK) {
        const int base = o0 + oc;

        // Wave-uniform x window (indices depend only on blockIdx / loop
        // counter) -> scalar loads into SGPRs. Clamp keeps tail reads in
        // bounds; clamped values only feed o >= out_len which are not stored.
        float xs[O_CHUNK + K_TAPS - 1];
        #pragma unroll
        for (int j = 0; j < O_CHUNK + K_TAPS - 1; ++j) {
            int xi = base + j;
            xi = (xi < L) ? xi : (L - 1);
            xs[j] = xb[xi];
        }

        #pragma unroll
        for (int oo = 0; oo < O_CHUNK; ++oo) {
            float acc = 0.0f;
            #pragma unroll
            for (int k = 0; k < K_TAPS; ++k)
                acc = fmaf(xs[oo + k], wr[k], acc);
            const int o = base + oo;
            if (o < out_len)
                yb[(size_t)(oc + oo) * F_FILT] = fmaxf(acc, 0.0f);
        }
    }
}

extern "C" void kernel_launch(void* const* d_in, const int* in_sizes, int n_in,
                              void* d_out, int out_size, void* d_ws, size_t ws_size,
                              hipStream_t stream) {
    const float* x = (const float*)d_in[0];   // 64*16384 fp32
    const float* w = (const float*)d_in[1];   // 128*16  fp32
    float*       y = (float*)d_out;           // 64*16369*128 fp32

    const int B = 64;
    const int L = in_sizes[0] / B;            // 16384
    const int out_len = L - K_TAPS + 1;       // 16369

    dim3 grid((out_len + O_TILE - 1) / O_TILE, B);
    dim3 block(F_FILT);
    SpecCnn1d_conv_kernel<<<grid, block, 0, stream>>>(x, w, y, L, out_len);
}